// Round 1
// baseline (101.120 us; speedup 1.0000x reference)
//
#include <hip/hip_runtime.h>
#include <math.h>

__device__ __forceinline__ float waveReduceSum(float v) {
    #pragma unroll
    for (int off = 32; off > 0; off >>= 1)
        v += __shfl_down(v, off, 64);
    return v;
}

// Kernel A: fused sum((a-p)^2) into acc[0] and sum(relu(P)^2) into acc[1]
__global__ void reduce_main(const float* __restrict__ a,
                            const float* __restrict__ p,
                            const float* __restrict__ Pm,
                            float* __restrict__ acc,
                            long nAP, long nP)
{
    float s0 = 0.f, s1 = 0.f;
    long tid = (long)blockIdx.x * blockDim.x + threadIdx.x;
    long stride = (long)gridDim.x * blockDim.x;

    const float4* a4 = (const float4*)a;
    const float4* p4 = (const float4*)p;
    long n4 = nAP >> 2;
    for (long i = tid; i < n4; i += stride) {
        float4 av = a4[i];
        float4 pv = p4[i];
        float d0 = av.x - pv.x;
        float d1 = av.y - pv.y;
        float d2 = av.z - pv.z;
        float d3 = av.w - pv.w;
        s0 += d0*d0 + d1*d1 + d2*d2 + d3*d3;
    }

    const float4* P4 = (const float4*)Pm;
    long nP4 = nP >> 2;
    for (long i = tid; i < nP4; i += stride) {
        float4 v = P4[i];
        float r0 = fmaxf(v.x, 0.f);
        float r1 = fmaxf(v.y, 0.f);
        float r2 = fmaxf(v.z, 0.f);
        float r3 = fmaxf(v.w, 0.f);
        s1 += r0*r0 + r1*r1 + r2*r2 + r3*r3;
    }

    s0 = waveReduceSum(s0);
    s1 = waveReduceSum(s1);

    __shared__ float sm0[4], sm1[4];
    int wave = threadIdx.x >> 6;
    int lane = threadIdx.x & 63;
    if (lane == 0) { sm0[wave] = s0; sm1[wave] = s1; }
    __syncthreads();
    if (threadIdx.x == 0) {
        atomicAdd(&acc[0], sm0[0] + sm0[1] + sm0[2] + sm0[3]);
        atomicAdd(&acc[1], sm1[0] + sm1[1] + sm1[2] + sm1[3]);
    }
}

// Kernel B: parameter_penalty = sum_{i,j} relu(P[ri,rj]) * safe_norm(S[ri]-S[rj])
// One wave per pair, 4 pairs per wave, 4 waves (256 threads) per block.
__global__ void pair_kernel(const float* __restrict__ S,
                            const float* __restrict__ Pm,
                            const int* __restrict__ ii,
                            const int* __restrict__ jj,
                            float* __restrict__ acc,
                            int Npair, int D, int K)
{
    int wave = threadIdx.x >> 6;
    int lane = threadIdx.x & 63;
    int totalPairs = Npair * Npair;
    int base = blockIdx.x * 16 + wave * 4;

    float local = 0.f;
    #pragma unroll
    for (int q = 0; q < 4; ++q) {
        int pair = base + q;
        if (pair >= totalPairs) break;
        int i = pair / Npair;
        int j = pair - i * Npair;
        int ri = ii[i];
        int rj = jj[j];
        const float4* Si = (const float4*)(S + (long)ri * D);
        const float4* Sj = (const float4*)(S + (long)rj * D);
        float d2 = 0.f;
        int n4 = D >> 2;                 // 256 float4 per row
        for (int k = lane; k < n4; k += 64) {
            float4 x = Si[k];
            float4 y = Sj[k];
            float e0 = x.x - y.x;
            float e1 = x.y - y.y;
            float e2 = x.z - y.z;
            float e3 = x.w - y.w;
            d2 += e0*e0 + e1*e1 + e2*e2 + e3*e3;
        }
        d2 = waveReduceSum(d2);
        if (lane == 0 && d2 > 0.f) {
            float pij = fmaxf(Pm[(long)ri * K + rj], 0.f);
            local += pij * sqrtf(d2);
        }
    }

    __shared__ float sm[4];
    if (lane == 0) sm[wave] = local;
    __syncthreads();
    if (threadIdx.x == 0)
        atomicAdd(&acc[2], sm[0] + sm[1] + sm[2] + sm[3]);
}

__global__ void finalize_kernel(const float* __restrict__ acc,
                                const float* __restrict__ lamb,
                                float* __restrict__ out)
{
    out[0] = sqrtf(acc[0]) + lamb[0] * (sqrtf(acc[1]) + acc[2]);
}

extern "C" void kernel_launch(void* const* d_in, const int* in_sizes, int n_in,
                              void* d_out, int out_size, void* d_ws, size_t ws_size,
                              hipStream_t stream) {
    const float* actual = (const float*)d_in[0];
    const float* pred   = (const float*)d_in[1];
    const float* lamb   = (const float*)d_in[2];
    const float* Pm     = (const float*)d_in[3];
    const float* S      = (const float*)d_in[4];
    const int*   ii     = (const int*)d_in[5];
    const int*   jj     = (const int*)d_in[6];
    float* out = (float*)d_out;
    float* acc = (float*)d_ws;

    long nAP  = in_sizes[0];            // 4096*4096
    long nP   = in_sizes[3];            // 2048*2048
    int  K    = (int)lround(sqrt((double)nP));
    int  Npair = in_sizes[5];
    int  D    = (int)(in_sizes[4] / K);

    hipMemsetAsync(acc, 0, 3 * sizeof(float), stream);

    reduce_main<<<2048, 256, 0, stream>>>(actual, pred, Pm, acc, nAP, nP);

    int totalPairs = Npair * Npair;
    int blocks = (totalPairs + 15) / 16;
    pair_kernel<<<blocks, 256, 0, stream>>>(S, Pm, ii, jj, acc, Npair, D, K);

    finalize_kernel<<<1, 1, 0, stream>>>(acc, lamb, out);
}

// Round 2
// 36.366 us; speedup vs baseline: 2.7806x; 2.7806x over previous
//
#include <hip/hip_runtime.h>
#include <math.h>

#define BR 1024   // reducer blocks
#define BP 1024   // pair blocks
#define TPB 256

__device__ __forceinline__ float waveReduceSum(float v) {
    #pragma unroll
    for (int off = 32; off > 0; off >>= 1)
        v += __shfl_down(v, off, 64);
    return v;
}

// Fused kernel.
// blocks [0, BP):      parameter_penalty pairs -> ws[2*BR + b]
// blocks [BP, BP+BR):  sum((a-p)^2) -> ws[rb], sum(relu(P)^2) -> ws[BR + rb]
__global__ __launch_bounds__(256, 8)
void fused_kernel(const float* __restrict__ a,
                  const float* __restrict__ p,
                  const float* __restrict__ Pm,
                  const float* __restrict__ S,
                  const int* __restrict__ ii,
                  const int* __restrict__ jj,
                  float* __restrict__ ws,
                  long nAP, long nP, int Npair, int D, int K)
{
    __shared__ float sm0[4], sm1[4];
    const int wave = threadIdx.x >> 6;
    const int lane = threadIdx.x & 63;
    const int bid  = blockIdx.x;

    if (bid < BP) {
        // ---- pair role: 16 pairs per block, 4 per wave ----
        const int totalPairs = Npair * Npair;
        int base = bid * 16 + wave * 4;
        float local = 0.f;
        #pragma unroll
        for (int q = 0; q < 4; ++q) {
            int pair = base + q;
            if (pair < totalPairs) {
                int i = pair / Npair;
                int j = pair - i * Npair;
                int ri = ii[i];
                int rj = jj[j];
                const float4* Si = (const float4*)(S + (long)ri * D);
                const float4* Sj = (const float4*)(S + (long)rj * D);
                float d2 = 0.f;
                int n4 = D >> 2;
                for (int k = lane; k < n4; k += 64) {
                    float4 x = Si[k];
                    float4 y = Sj[k];
                    float e0 = x.x - y.x;
                    float e1 = x.y - y.y;
                    float e2 = x.z - y.z;
                    float e3 = x.w - y.w;
                    d2 += e0*e0 + e1*e1 + e2*e2 + e3*e3;
                }
                d2 = waveReduceSum(d2);
                if (lane == 0 && d2 > 0.f)
                    local += fmaxf(Pm[(long)ri * K + rj], 0.f) * sqrtf(d2);
            }
        }
        if (lane == 0) sm0[wave] = local;
        __syncthreads();
        if (threadIdx.x == 0)
            ws[2 * BR + bid] = sm0[0] + sm0[1] + sm0[2] + sm0[3];
    } else {
        // ---- reducer role ----
        const int rb = bid - BP;
        const long tid    = (long)rb * TPB + threadIdx.x;
        const long stride = (long)BR * TPB;

        const float4* a4 = (const float4*)a;
        const float4* p4 = (const float4*)p;
        long n4 = nAP >> 2;

        float s0a = 0.f, s0b = 0.f, s0c = 0.f, s0d = 0.f;
        long i = tid;
        for (; i + 3 * stride < n4; i += 4 * stride) {
            float4 av0 = a4[i];
            float4 av1 = a4[i + stride];
            float4 av2 = a4[i + 2 * stride];
            float4 av3 = a4[i + 3 * stride];
            float4 pv0 = p4[i];
            float4 pv1 = p4[i + stride];
            float4 pv2 = p4[i + 2 * stride];
            float4 pv3 = p4[i + 3 * stride];
            {
                float d0 = av0.x - pv0.x, d1 = av0.y - pv0.y;
                float d2 = av0.z - pv0.z, d3 = av0.w - pv0.w;
                s0a += d0*d0 + d1*d1 + d2*d2 + d3*d3;
            }
            {
                float d0 = av1.x - pv1.x, d1 = av1.y - pv1.y;
                float d2 = av1.z - pv1.z, d3 = av1.w - pv1.w;
                s0b += d0*d0 + d1*d1 + d2*d2 + d3*d3;
            }
            {
                float d0 = av2.x - pv2.x, d1 = av2.y - pv2.y;
                float d2 = av2.z - pv2.z, d3 = av2.w - pv2.w;
                s0c += d0*d0 + d1*d1 + d2*d2 + d3*d3;
            }
            {
                float d0 = av3.x - pv3.x, d1 = av3.y - pv3.y;
                float d2 = av3.z - pv3.z, d3 = av3.w - pv3.w;
                s0d += d0*d0 + d1*d1 + d2*d2 + d3*d3;
            }
        }
        for (; i < n4; i += stride) {
            float4 av = a4[i];
            float4 pv = p4[i];
            float d0 = av.x - pv.x, d1 = av.y - pv.y;
            float d2 = av.z - pv.z, d3 = av.w - pv.w;
            s0a += d0*d0 + d1*d1 + d2*d2 + d3*d3;
        }

        // relu(P)^2 sum, unroll 2
        const float4* P4 = (const float4*)Pm;
        long nP4 = nP >> 2;
        float s1a = 0.f, s1b = 0.f;
        i = tid;
        for (; i + stride < nP4; i += 2 * stride) {
            float4 v0 = P4[i];
            float4 v1 = P4[i + stride];
            {
                float r0 = fmaxf(v0.x, 0.f), r1 = fmaxf(v0.y, 0.f);
                float r2 = fmaxf(v0.z, 0.f), r3 = fmaxf(v0.w, 0.f);
                s1a += r0*r0 + r1*r1 + r2*r2 + r3*r3;
            }
            {
                float r0 = fmaxf(v1.x, 0.f), r1 = fmaxf(v1.y, 0.f);
                float r2 = fmaxf(v1.z, 0.f), r3 = fmaxf(v1.w, 0.f);
                s1b += r0*r0 + r1*r1 + r2*r2 + r3*r3;
            }
        }
        for (; i < nP4; i += stride) {
            float4 v = P4[i];
            float r0 = fmaxf(v.x, 0.f), r1 = fmaxf(v.y, 0.f);
            float r2 = fmaxf(v.z, 0.f), r3 = fmaxf(v.w, 0.f);
            s1a += r0*r0 + r1*r1 + r2*r2 + r3*r3;
        }

        float s0 = waveReduceSum(s0a + s0b + s0c + s0d);
        float s1 = waveReduceSum(s1a + s1b);
        if (lane == 0) { sm0[wave] = s0; sm1[wave] = s1; }
        __syncthreads();
        if (threadIdx.x == 0) {
            ws[rb]      = sm0[0] + sm0[1] + sm0[2] + sm0[3];
            ws[BR + rb] = sm1[0] + sm1[1] + sm1[2] + sm1[3];
        }
    }
}

__global__ void finalize_kernel(const float* __restrict__ ws,
                                const float* __restrict__ lamb,
                                float* __restrict__ out)
{
    float a0 = 0.f, a1 = 0.f, a2 = 0.f;
    for (int i = threadIdx.x; i < BR; i += TPB) {
        a0 += ws[i];
        a1 += ws[BR + i];
    }
    for (int i = threadIdx.x; i < BP; i += TPB)
        a2 += ws[2 * BR + i];

    a0 = waveReduceSum(a0);
    a1 = waveReduceSum(a1);
    a2 = waveReduceSum(a2);

    __shared__ float m0[4], m1[4], m2[4];
    int wave = threadIdx.x >> 6;
    int lane = threadIdx.x & 63;
    if (lane == 0) { m0[wave] = a0; m1[wave] = a1; m2[wave] = a2; }
    __syncthreads();
    if (threadIdx.x == 0) {
        float A0 = m0[0] + m0[1] + m0[2] + m0[3];
        float A1 = m1[0] + m1[1] + m1[2] + m1[3];
        float A2 = m2[0] + m2[1] + m2[2] + m2[3];
        out[0] = sqrtf(A0) + lamb[0] * (sqrtf(A1) + A2);
    }
}

extern "C" void kernel_launch(void* const* d_in, const int* in_sizes, int n_in,
                              void* d_out, int out_size, void* d_ws, size_t ws_size,
                              hipStream_t stream) {
    const float* actual = (const float*)d_in[0];
    const float* pred   = (const float*)d_in[1];
    const float* lamb   = (const float*)d_in[2];
    const float* Pm     = (const float*)d_in[3];
    const float* S      = (const float*)d_in[4];
    const int*   ii     = (const int*)d_in[5];
    const int*   jj     = (const int*)d_in[6];
    float* out = (float*)d_out;
    float* ws  = (float*)d_ws;

    long nAP   = in_sizes[0];                       // 4096*4096
    long nP    = in_sizes[3];                       // 2048*2048
    int  K     = (int)lround(sqrt((double)nP));     // 2048
    int  Npair = in_sizes[5];                       // 128
    int  D     = (int)(in_sizes[4] / K);            // 1024

    fused_kernel<<<BP + BR, TPB, 0, stream>>>(actual, pred, Pm, S, ii, jj, ws,
                                              nAP, nP, Npair, D, K);
    finalize_kernel<<<1, TPB, 0, stream>>>(ws, lamb, out);
}